// Round 2
// baseline (36161.780 us; speedup 1.0000x reference)
//
#include <hip/hip_runtime.h>

#define SEQ  1000
#define IDIM 900
#define H    4096
#define NBUF 4   // rotating partial buffers; drift bound is 2 (diameter-2 dependency graph)

// ---------------------------------------------------------------------------
__device__ __forceinline__ float tanh_fast(float x) {
    float ax = __builtin_fabsf(x);
    float e  = __expf(-2.0f * ax);
    float t  = (1.0f - e) / (1.0f + e);
    return __builtin_copysignf(t, x);
}

// ---------------------------------------------------------------------------
// Persistent recurrent kernel.
// Grid: 256 blocks x 1024 threads (16 waves), cooperative (1 block/CU).
// q = b>>2 owns rows [64q, 64q+64); m = b&3 owns cols [1024m, +1024).
// wave w covers cols [1024m + 64w, +64); lane = row offset in quad.
// Each lane holds 64 fp32 W_hh weights in VGPRs (fits 128-VGPR budget — the
// round-1 128/lane version spilled: VGPR_Count=100 < 128 needed).
// Per step: block (q,m) stores 64 partial row sums into part[slot][q][m][*],
// sets flags[b] = step. Consumer (q,m) of step t polls the 64 flags of
// blocks {q' in [16m,16m+16), m' in 0..4}, then reads+reduces 4 partials/col.
// ---------------------------------------------------------------------------
__global__ __launch_bounds__(1024, 4) void esn_recurrent(
    const float* __restrict__ Whh,     // H*H row-major
    const float* __restrict__ pre_in,  // SEQ*H = X @ W_ih^T  (ws)
    float*       __restrict__ states,  // SEQ*H (inside d_out)
    float*       __restrict__ part,    // NBUF*64*4*64 floats (scratch in d_out)
    unsigned int* __restrict__ flags)  // 256 (zeroed before launch)
{
    const int b    = blockIdx.x;
    const int q    = b >> 2;           // 0..63
    const int m    = b & 3;            // 0..3
    const int tid  = threadIdx.x;
    const int wave = tid >> 6;         // 0..15
    const int lane = tid & 63;         // 0..63
    const int row  = (q << 6) + lane;  // my output row

    // ---- 64 register-resident weights ----
    float w[64];
    {
        const float* wp = Whh + (size_t)row * H + (m << 10) + (wave << 6);
        #pragma unroll
        for (int k = 0; k < 64; k += 4) {
            float4 v = *(const float4*)(wp + k);
            w[k] = v.x; w[k + 1] = v.y; w[k + 2] = v.z; w[k + 3] = v.w;
        }
    }

    __shared__ float s_lds[1024];      // s[t] slice for my 1024 cols
    __shared__ float red[16][65];      // cross-wave reduction (+1 pad)

    for (int t = 0; t < SEQ; ++t) {
        // ---- 1. obtain s[t] for my cols ----
        float sv;
        if (t == 0) {
            sv = tanh_fast(pre_in[(m << 10) + tid]);
        } else {
            if (wave == 0) {
                // producers of my col slice: flag indices [64m, 64m+64)
                const unsigned want = (unsigned)t;
                while (__hip_atomic_load(&flags[(m << 6) + lane], __ATOMIC_RELAXED,
                                         __HIP_MEMORY_SCOPE_AGENT) < want) {
                    __builtin_amdgcn_s_sleep(1);
                }
            }
            __syncthreads();
            __builtin_amdgcn_fence(__ATOMIC_ACQUIRE, "agent");
            const int slot = t & (NBUF - 1);
            const int qq   = (m << 4) + (tid >> 6);        // producing quad
            float* pb = part + (((size_t)slot * 64 + qq) * 4) * 64 + (tid & 63);
            float sum = 0.f;
            #pragma unroll
            for (int mm = 0; mm < 4; ++mm)
                sum += __hip_atomic_load(pb + (mm << 6), __ATOMIC_RELAXED,
                                         __HIP_MEMORY_SCOPE_AGENT);
            sv = tanh_fast(sum);
        }
        s_lds[tid] = sv;
        if (q == 0) states[(size_t)t * H + (m << 10) + tid] = sv;
        __syncthreads();

        if (t == SEQ - 1) break;

        // ---- 2. partial dot: my row x my 64 cols (s_lds reads wave-uniform) ----
        float a0 = 0.f, a1 = 0.f, a2 = 0.f, a3 = 0.f;
        {
            const float4* sv4 = (const float4*)(s_lds + (wave << 6));
            #pragma unroll
            for (int j = 0; j < 16; ++j) {
                float4 v = sv4[j];
                a0 += w[4 * j + 0] * v.x;
                a1 += w[4 * j + 1] * v.y;
                a2 += w[4 * j + 2] * v.z;
                a3 += w[4 * j + 3] * v.w;
            }
        }
        red[wave][lane] = (a0 + a1) + (a2 + a3);
        __syncthreads();

        // ---- 3. cross-wave reduce, publish partial, release flag ----
        if (wave == 0) {
            float sum = 0.f;
            #pragma unroll
            for (int ww = 0; ww < 16; ++ww) sum += red[ww][lane];
            if (m == 0) sum += pre_in[(size_t)(t + 1) * H + row];
            const int slot = (t + 1) & (NBUF - 1);
            __hip_atomic_store(part + (((size_t)slot * 64 + q) * 4 + m) * 64 + lane,
                               sum, __ATOMIC_RELAXED, __HIP_MEMORY_SCOPE_AGENT);
            __builtin_amdgcn_fence(__ATOMIC_RELEASE, "agent");
            if (lane == 0)
                __hip_atomic_store(&flags[b], (unsigned)(t + 1),
                                   __ATOMIC_RELAXED, __HIP_MEMORY_SCOPE_AGENT);
        }
        // top-of-loop __syncthreads (consume phase) protects s_lds/red reuse
    }
}

// ---------------------------------------------------------------------------
// Generic fp32 tiled GEMM:  C[MxN] = A[MxK] * B[NxK]^T   (both row-major)
// mode 0: A plain (lda). mode 1: virtual ext row t: [1, X[t], S[t]].
// ---------------------------------------------------------------------------
#define BM 64
#define BN 64
#define BK 32

__global__ __launch_bounds__(256) void gemm_abt(
    const float* __restrict__ A, int lda,
    const float* __restrict__ B, int ldb,
    float*       __restrict__ C, int ldc,
    int M, int N, int K, int mode,
    const float* __restrict__ X, const float* __restrict__ S)
{
    __shared__ float As[BK][BM + 1];
    __shared__ float Bs[BK][BN + 1];

    const int tid = threadIdx.x;
    const int n0  = blockIdx.x * BN;
    const int m0  = blockIdx.y * BM;
    const int tx  = tid & 15;
    const int ty  = tid >> 4;

    float c[4][4] = {};

    for (int k0 = 0; k0 < K; k0 += BK) {
        #pragma unroll
        for (int p = 0; p < 8; ++p) {
            const int idx = tid + p * 256;
            const int mm  = idx >> 5;
            const int kk  = idx & 31;
            const int gk  = k0 + kk;

            float av = 0.f;
            const int gm = m0 + mm;
            if (gm < M && gk < K) {
                if (mode == 0) {
                    av = A[(size_t)gm * lda + gk];
                } else {
                    if (gk == 0)          av = 1.0f;
                    else if (gk <= IDIM)  av = X[(size_t)gm * IDIM + (gk - 1)];
                    else                  av = S[(size_t)gm * H + (gk - 1 - IDIM)];
                }
            }
            As[kk][mm] = av;

            float bv = 0.f;
            const int gn = n0 + mm;
            if (gn < N && gk < K) bv = B[(size_t)gn * ldb + gk];
            Bs[kk][mm] = bv;
        }
        __syncthreads();

        #pragma unroll
        for (int kk = 0; kk < BK; ++kk) {
            float a[4], bb[4];
            #pragma unroll
            for (int i = 0; i < 4; ++i) a[i]  = As[kk][ty * 4 + i];
            #pragma unroll
            for (int j = 0; j < 4; ++j) bb[j] = Bs[kk][tx * 4 + j];
            #pragma unroll
            for (int i = 0; i < 4; ++i)
                #pragma unroll
                for (int j = 0; j < 4; ++j)
                    c[i][j] += a[i] * bb[j];
        }
        __syncthreads();
    }

    #pragma unroll
    for (int i = 0; i < 4; ++i) {
        const int gm = m0 + ty * 4 + i;
        if (gm >= M) continue;
        #pragma unroll
        for (int j = 0; j < 4; ++j) {
            const int gn = n0 + tx * 4 + j;
            if (gn < N) C[(size_t)gm * ldc + gn] = c[i][j];
        }
    }
}

// ---------------------------------------------------------------------------
// Launcher
// ---------------------------------------------------------------------------
extern "C" void kernel_launch(void* const* d_in, const int* in_sizes, int n_in,
                              void* d_out, int out_size, void* d_ws, size_t ws_size,
                              hipStream_t stream) {
    const float* inputs = (const float*)d_in[0];
    // d_in[1] = initial state (zeros) — folded out
    const float* W_ih   = (const float*)d_in[2];
    const float* W_hh   = (const float*)d_in[3];
    const float* W_out  = (const float*)d_in[4];

    float* out    = (float*)d_out;                 // SEQ*IDIM
    float* states = out + (size_t)SEQ * IDIM;      // SEQ*H

    float* pre_in = (float*)d_ws;                  // SEQ*H fp32 (16.4 MB)

    // Scratch for the recurrence lives in the outputs region of d_out
    // (re-poisoned before each launch; phase 2 overwrites it afterwards):
    //   part : NBUF*64*4*64 floats = 65536 floats (256 KB)
    //   flags: 256 u32
    float* part = out;
    unsigned int* flags = (unsigned int*)(out + (size_t)NBUF * 64 * 4 * 64);

    hipMemsetAsync(flags, 0, 256 * sizeof(unsigned int), stream);

    // Phase 0: pre_in[t][r] = sum_i X[t][i] * W_ih[r][i]
    gemm_abt<<<dim3(H / BN, (SEQ + BM - 1) / BM), 256, 0, stream>>>(
        inputs, IDIM, W_ih, IDIM, pre_in, H, SEQ, H, IDIM, 0, nullptr, nullptr);

    // Phase 1: persistent sequential recurrence
    {
        const float* whh_p = W_hh;
        const float* pin_p = pre_in;
        float* st_p = states;
        float* part_p = part;
        unsigned int* fl_p = flags;
        void* args[] = { (void*)&whh_p, (void*)&pin_p, (void*)&st_p,
                         (void*)&part_p, (void*)&fl_p };
        hipLaunchCooperativeKernel((const void*)esn_recurrent,
                                   dim3(256), dim3(1024), args, 0, stream);
    }

    // Phase 2: outputs[t][i] = sum_k ext[t][k] * W_out[i][k]
    gemm_abt<<<dim3((IDIM + BN - 1) / BN, (SEQ + BM - 1) / BM), 256, 0, stream>>>(
        nullptr, 0, W_out, 1 + IDIM + H, out, IDIM,
        SEQ, IDIM, 1 + IDIM + H, 1, inputs, states);
}

// Round 3
// 35986.682 us; speedup vs baseline: 1.0049x; 1.0049x over previous
//
#include <hip/hip_runtime.h>

#define SEQ  1000
#define IDIM 900
#define H    4096
#define NBUF 4   // rotating partial buffers; drift bound is 2 (diameter-2 dependency graph)

// ---------------------------------------------------------------------------
__device__ __forceinline__ float tanh_fast(float x) {
    float ax = __builtin_fabsf(x);
    float e  = __expf(-2.0f * ax);
    float t  = (1.0f - e) / (1.0f + e);
    return __builtin_copysignf(t, x);
}

// ---------------------------------------------------------------------------
// Persistent recurrent kernel.
// Grid: 256 blocks x 1024 threads (16 waves), cooperative (1 block/CU).
// q = b>>2 owns rows [64q, 64q+64); m = b&3 owns cols [1024m, +1024).
// wave w covers cols [1024m + 64w, +64); lane = row offset in quad.
// Each lane holds 64 fp32 W_hh weights, PINNED in VGPRs via an inline-asm
// value barrier — rounds 1/2 proved the compiler otherwise rematerializes
// the loads inside the step loop (VGPR_Count=100/56 < needed), turning the
// kernel into a 64 MB/step L3 stream (~1.8 TB/s => 35 us/step).
// ---------------------------------------------------------------------------
__global__ __launch_bounds__(1024, 4) void esn_recurrent(
    const float* __restrict__ Whh,     // H*H row-major
    const float* __restrict__ pre_in,  // SEQ*H = X @ W_ih^T  (ws)
    float*       __restrict__ states,  // SEQ*H (inside d_out)
    float*       __restrict__ part,    // NBUF*64*4*64 floats (scratch in d_out)
    unsigned int* __restrict__ flags)  // 256 (zeroed before launch)
{
    const int b    = blockIdx.x;
    const int q    = b >> 2;           // 0..63
    const int m    = b & 3;            // 0..3
    const int tid  = threadIdx.x;
    const int wave = tid >> 6;         // 0..15
    const int lane = tid & 63;         // 0..63
    const int row  = (q << 6) + lane;  // my output row

    // ---- 64 register-resident weights (pinned) ----
    float w[64];
    {
        const float* wp = Whh + (size_t)row * H + (m << 10) + (wave << 6);
        #pragma unroll
        for (int k = 0; k < 64; k += 4) {
            float4 v = *(const float4*)(wp + k);
            w[k] = v.x; w[k + 1] = v.y; w[k + 2] = v.z; w[k + 3] = v.w;
        }
    }
    // Opaque value barrier: w[k] is now defined by asm, not by a load the
    // compiler can sink/remat into the loop.
    #pragma unroll
    for (int k = 0; k < 64; ++k) asm volatile("" : "+v"(w[k]));

    __shared__ float s_lds[1024];      // s[t] slice for my 1024 cols
    __shared__ float red[16][65];      // cross-wave reduction (+1 pad)

    for (int t = 0; t < SEQ; ++t) {
        // ---- 1. obtain s[t] for my cols ----
        float sv;
        if (t == 0) {
            sv = tanh_fast(pre_in[(m << 10) + tid]);
        } else {
            if (wave == 0) {
                // producers of my col slice: flag indices [64m, 64m+64)
                const unsigned want = (unsigned)t;
                while (__hip_atomic_load(&flags[(m << 6) + lane], __ATOMIC_RELAXED,
                                         __HIP_MEMORY_SCOPE_AGENT) < want) {
                    __builtin_amdgcn_s_sleep(1);
                }
            }
            __syncthreads();
            __builtin_amdgcn_fence(__ATOMIC_ACQUIRE, "agent");
            const int slot = t & (NBUF - 1);
            const int qq   = (m << 4) + (tid >> 6);        // producing quad
            float* pb = part + (((size_t)slot * 64 + qq) * 4) * 64 + (tid & 63);
            float sum = 0.f;
            #pragma unroll
            for (int mm = 0; mm < 4; ++mm)
                sum += __hip_atomic_load(pb + (mm << 6), __ATOMIC_RELAXED,
                                         __HIP_MEMORY_SCOPE_AGENT);
            sv = tanh_fast(sum);
        }
        s_lds[tid] = sv;
        if (q == 0) states[(size_t)t * H + (m << 10) + tid] = sv;
        __syncthreads();

        if (t == SEQ - 1) break;

        // ---- 2. partial dot: my row x my 64 cols (s_lds reads wave-uniform) ----
        float a0 = 0.f, a1 = 0.f, a2 = 0.f, a3 = 0.f;
        {
            const float4* sv4 = (const float4*)(s_lds + (wave << 6));
            #pragma unroll
            for (int j = 0; j < 16; ++j) {
                float4 v = sv4[j];
                a0 += w[4 * j + 0] * v.x;
                a1 += w[4 * j + 1] * v.y;
                a2 += w[4 * j + 2] * v.z;
                a3 += w[4 * j + 3] * v.w;
            }
        }
        red[wave][lane] = (a0 + a1) + (a2 + a3);
        __syncthreads();

        // ---- 3. cross-wave reduce, publish partial, release flag ----
        if (wave == 0) {
            float sum = 0.f;
            #pragma unroll
            for (int ww = 0; ww < 16; ++ww) sum += red[ww][lane];
            if (m == 0) sum += pre_in[(size_t)(t + 1) * H + row];
            const int slot = (t + 1) & (NBUF - 1);
            __hip_atomic_store(part + (((size_t)slot * 64 + q) * 4 + m) * 64 + lane,
                               sum, __ATOMIC_RELAXED, __HIP_MEMORY_SCOPE_AGENT);
            __builtin_amdgcn_fence(__ATOMIC_RELEASE, "agent");
            if (lane == 0)
                __hip_atomic_store(&flags[b], (unsigned)(t + 1),
                                   __ATOMIC_RELAXED, __HIP_MEMORY_SCOPE_AGENT);
        }
        // top-of-loop __syncthreads (consume phase) protects s_lds/red reuse
    }
}

// ---------------------------------------------------------------------------
// Generic fp32 tiled GEMM:  C[MxN] = A[MxK] * B[NxK]^T   (both row-major)
// mode 0: A plain (lda). mode 1: virtual ext row t: [1, X[t], S[t]].
// ---------------------------------------------------------------------------
#define BM 64
#define BN 64
#define BK 32

__global__ __launch_bounds__(256) void gemm_abt(
    const float* __restrict__ A, int lda,
    const float* __restrict__ B, int ldb,
    float*       __restrict__ C, int ldc,
    int M, int N, int K, int mode,
    const float* __restrict__ X, const float* __restrict__ S)
{
    __shared__ float As[BK][BM + 1];
    __shared__ float Bs[BK][BN + 1];

    const int tid = threadIdx.x;
    const int n0  = blockIdx.x * BN;
    const int m0  = blockIdx.y * BM;
    const int tx  = tid & 15;
    const int ty  = tid >> 4;

    float c[4][4] = {};

    for (int k0 = 0; k0 < K; k0 += BK) {
        #pragma unroll
        for (int p = 0; p < 8; ++p) {
            const int idx = tid + p * 256;
            const int mm  = idx >> 5;
            const int kk  = idx & 31;
            const int gk  = k0 + kk;

            float av = 0.f;
            const int gm = m0 + mm;
            if (gm < M && gk < K) {
                if (mode == 0) {
                    av = A[(size_t)gm * lda + gk];
                } else {
                    if (gk == 0)          av = 1.0f;
                    else if (gk <= IDIM)  av = X[(size_t)gm * IDIM + (gk - 1)];
                    else                  av = S[(size_t)gm * H + (gk - 1 - IDIM)];
                }
            }
            As[kk][mm] = av;

            float bv = 0.f;
            const int gn = n0 + mm;
            if (gn < N && gk < K) bv = B[(size_t)gn * ldb + gk];
            Bs[kk][mm] = bv;
        }
        __syncthreads();

        #pragma unroll
        for (int kk = 0; kk < BK; ++kk) {
            float a[4], bb[4];
            #pragma unroll
            for (int i = 0; i < 4; ++i) a[i]  = As[kk][ty * 4 + i];
            #pragma unroll
            for (int j = 0; j < 4; ++j) bb[j] = Bs[kk][tx * 4 + j];
            #pragma unroll
            for (int i = 0; i < 4; ++i)
                #pragma unroll
                for (int j = 0; j < 4; ++j)
                    c[i][j] += a[i] * bb[j];
        }
        __syncthreads();
    }

    #pragma unroll
    for (int i = 0; i < 4; ++i) {
        const int gm = m0 + ty * 4 + i;
        if (gm >= M) continue;
        #pragma unroll
        for (int j = 0; j < 4; ++j) {
            const int gn = n0 + tx * 4 + j;
            if (gn < N) C[(size_t)gm * ldc + gn] = c[i][j];
        }
    }
}

// ---------------------------------------------------------------------------
// Launcher
// ---------------------------------------------------------------------------
extern "C" void kernel_launch(void* const* d_in, const int* in_sizes, int n_in,
                              void* d_out, int out_size, void* d_ws, size_t ws_size,
                              hipStream_t stream) {
    const float* inputs = (const float*)d_in[0];
    // d_in[1] = initial state (zeros) — folded out
    const float* W_ih   = (const float*)d_in[2];
    const float* W_hh   = (const float*)d_in[3];
    const float* W_out  = (const float*)d_in[4];

    float* out    = (float*)d_out;                 // SEQ*IDIM
    float* states = out + (size_t)SEQ * IDIM;      // SEQ*H

    float* pre_in = (float*)d_ws;                  // SEQ*H fp32 (16.4 MB)

    // Scratch for the recurrence lives in the outputs region of d_out
    // (re-poisoned before each launch; phase 2 overwrites it afterwards):
    //   part : NBUF*64*4*64 floats = 65536 floats (256 KB)
    //   flags: 256 u32
    float* part = out;
    unsigned int* flags = (unsigned int*)(out + (size_t)NBUF * 64 * 4 * 64);

    hipMemsetAsync(flags, 0, 256 * sizeof(unsigned int), stream);

    // Phase 0: pre_in[t][r] = sum_i X[t][i] * W_ih[r][i]
    gemm_abt<<<dim3(H / BN, (SEQ + BM - 1) / BM), 256, 0, stream>>>(
        inputs, IDIM, W_ih, IDIM, pre_in, H, SEQ, H, IDIM, 0, nullptr, nullptr);

    // Phase 1: persistent sequential recurrence
    {
        const float* whh_p = W_hh;
        const float* pin_p = pre_in;
        float* st_p = states;
        float* part_p = part;
        unsigned int* fl_p = flags;
        void* args[] = { (void*)&whh_p, (void*)&pin_p, (void*)&st_p,
                         (void*)&part_p, (void*)&fl_p };
        hipLaunchCooperativeKernel((const void*)esn_recurrent,
                                   dim3(256), dim3(1024), args, 0, stream);
    }

    // Phase 2: outputs[t][i] = sum_k ext[t][k] * W_out[i][k]
    gemm_abt<<<dim3((IDIM + BN - 1) / BN, (SEQ + BM - 1) / BM), 256, 0, stream>>>(
        nullptr, 0, W_out, 1 + IDIM + H, out, IDIM,
        SEQ, IDIM, 1 + IDIM + H, 1, inputs, states);
}